// Round 1
// baseline (249.385 us; speedup 1.0000x reference)
//
#include <hip/hip_runtime.h>
#include <hip/hip_bf16.h>

// Dilate = 5x5 per-channel max filter, SAME padding, over (64,384,384,3) f32.
// Separable: horizontal 5-max then vertical 5-max, LDS-tiled.
//
// Tile: 32x32 output pixels x 3 channels per block.
//   s_in : (32+4) rows x (32+4)*3 floats  = 36*108 = 3888 f (15.6 KB)
//   s_h  : (32+4) rows x  32*3    floats  = 36*96  = 3456 f (13.8 KB)
// All LDS sweeps are stride-1 in the flattened index -> conflict-free.

#define B 64
#define H 384
#define W 384
#define C 3
#define KHALF 2            // k=5 -> halo 2
#define TW 32
#define TH 32
#define INW (TW + 2*KHALF)     // 36
#define INH (TH + 2*KHALF)     // 36
#define INWC (INW * C)         // 108
#define TWC (TW * C)           // 96
#define ROWF (W * C)           // 1152 floats per (b,h) row
#define TILES_W (W / TW)       // 12
#define TILES_H (H / TH)       // 12

__global__ __launch_bounds__(256) void dilate5_kernel(
    const float* __restrict__ in, float* __restrict__ out) {
  __shared__ float s_in[INH * INWC];
  __shared__ float s_h[INH * TWC];

  const int tile = blockIdx.x;
  const int tx = tile % TILES_W;
  const int rest = tile / TILES_W;
  const int ty = rest % TILES_H;
  const int b = rest / TILES_H;

  const int w0 = tx * TW;          // output pixel base
  const int h0 = ty * TH;
  const size_t img_off = (size_t)b * (size_t)H * ROWF;
  const float* __restrict__ img = in + img_off;
  float* __restrict__ outimg = out + img_off;

  const int gc0 = w0 * C - KHALF * C;   // global float-col base (may be <0)

  // ---- Stage 1: global -> LDS (halo tile), OOB = -inf ----
  for (int idx = threadIdx.x; idx < INH * INWC; idx += 256) {
    const int r = idx / INWC;          // 0..35
    const int c = idx % INWC;          // 0..107
    const int gh = h0 - KHALF + r;
    const int gc = gc0 + c;
    float v = -3.402823466e+38f;
    if (gh >= 0 && gh < H && gc >= 0 && gc < ROWF)
      v = img[(size_t)gh * ROWF + gc];
    s_in[idx] = v;
  }
  __syncthreads();

  // ---- Stage 2: horizontal 5-max (stride C=3 in float-cols) ----
  // output col wc = w*3+c maps to s_in cols wc + dw*3, dw=0..4
  for (int idx = threadIdx.x; idx < INH * TWC; idx += 256) {
    const int r = idx / TWC;
    const int wc = idx % TWC;
    const float* p = &s_in[r * INWC + wc];
    float m = p[0];
    m = fmaxf(m, p[3]);
    m = fmaxf(m, p[6]);
    m = fmaxf(m, p[9]);
    m = fmaxf(m, p[12]);
    s_h[idx] = m;
  }
  __syncthreads();

  // ---- Stage 3: vertical 5-max + coalesced store ----
  for (int idx = threadIdx.x; idx < TH * TWC; idx += 256) {
    const int r = idx / TWC;           // output row in tile
    const int wc = idx % TWC;
    const float* p = &s_h[r * TWC + wc];
    float m = p[0];
    m = fmaxf(m, p[1 * TWC]);
    m = fmaxf(m, p[2 * TWC]);
    m = fmaxf(m, p[3 * TWC]);
    m = fmaxf(m, p[4 * TWC]);
    outimg[(size_t)(h0 + r) * ROWF + w0 * C + wc] = m;
  }
}

extern "C" void kernel_launch(void* const* d_in, const int* in_sizes, int n_in,
                              void* d_out, int out_size, void* d_ws, size_t ws_size,
                              hipStream_t stream) {
  const float* images = (const float*)d_in[0];
  float* out = (float*)d_out;
  const int nblocks = B * TILES_H * TILES_W;  // 64*12*12 = 9216
  dilate5_kernel<<<nblocks, 256, 0, stream>>>(images, out);
}

// Round 2
// 222.011 us; speedup vs baseline: 1.1233x; 1.1233x over previous
//
#include <hip/hip_runtime.h>
#include <hip/hip_bf16.h>
#include <math.h>

// Dilate = 5x5 per-channel max filter, SAME padding, (64,384,384,3) f32.
// Separable. Per 32x32-px tile (one block, 192 threads):
//   P1: 144 threads (4/row x 36 halo rows) load a 40-float aligned register
//       window (10x float4) from global, compute 24 horizontal 5-max floats
//       (taps are static component offsets: stride 3 = channels), write the
//       hmax row to LDS as 6x ds_write_b128.  OOB float4s -> -inf.
//   P2: 192 threads (24 col-strips x 8 row-groups) read 8 hmax rows as
//       ds_read_b128, vertical 5-max over a 4-row sliding group, float4 store.
// Only hmax rows touch LDS (14.4 KB) -> ~450 LDS cycles/block vs ~1630 before.

#define B 64
#define H 384
#define W 384
#define C 3
#define ROWF (W * C)          // 1152 floats per image row
#define TW 32                 // tile px wide  -> 96 out floats
#define TH 32                 // tile px tall
#define HROWS (TH + 4)        // 36 hmax rows (incl. vertical halo)
#define SSTRIDE 100           // hmax LDS row stride in floats (96 + 4 pad)
#define TILES_W (W / TW)      // 12
#define TILES_H (H / TH)      // 12
#define NEGINF (-3.402823466e+38f)

__device__ __forceinline__ float4 max4(float4 a, float4 b) {
  return make_float4(fmaxf(a.x, b.x), fmaxf(a.y, b.y),
                     fmaxf(a.z, b.z), fmaxf(a.w, b.w));
}

__global__ __launch_bounds__(192) void dilate5_kernel(
    const float* __restrict__ in, float* __restrict__ out) {
  __shared__ float s_h[HROWS * SSTRIDE];   // 14.4 KB

  const int tile = blockIdx.x;
  const int tx = tile % TILES_W;
  const int rest = tile / TILES_W;
  const int ty = rest % TILES_H;
  const int b = rest / TILES_H;

  const int w0f = tx * (TW * C);     // tile base in floats within a row (mult of 4)
  const int h0 = ty * TH;
  const float* __restrict__ img = in + (size_t)b * H * ROWF;
  float* __restrict__ outimg = out + (size_t)b * H * ROWF;

  const int t = threadIdx.x;

  // ---- P1: load + horizontal 5-max -> LDS ----
  if (t < 4 * HROWS) {
    const int r = t >> 2;            // 0..35 halo row
    const int c = t & 3;             // quarter of the row (24 out floats each)
    const int gh = h0 - 2 + r;
    const int gbase = w0f + c * 24 - 8;   // aligned window start (mult of 4)

    float w[40];
    if (gh >= 0 && gh < H) {
      const float* rowp = img + (size_t)gh * ROWF;
#pragma unroll
      for (int i = 0; i < 10; ++i) {
        const int col = gbase + 4 * i;
        float4 v;
        if (col >= 0 && col <= ROWF - 4) {
          v = *reinterpret_cast<const float4*>(rowp + col);
        } else {
          v = make_float4(NEGINF, NEGINF, NEGINF, NEGINF);
        }
        w[4 * i + 0] = v.x; w[4 * i + 1] = v.y;
        w[4 * i + 2] = v.z; w[4 * i + 3] = v.w;
      }
    } else {
#pragma unroll
      for (int i = 0; i < 40; ++i) w[i] = NEGINF;
    }

    // out float j (0..23) at global col w0f + c*24 + j; taps cols -6..+6 step 3
    // -> window indices j+2+3t, t=0..4  (window[0] = gbase = out base - 8)
    float h[24];
#pragma unroll
    for (int j = 0; j < 24; ++j) {
      float m = fmaxf(fmaxf(w[j + 2], w[j + 5]), fmaxf(w[j + 8], w[j + 11]));
      h[j] = fmaxf(m, w[j + 14]);
    }

    float* dst = &s_h[r * SSTRIDE + c * 24];
#pragma unroll
    for (int q = 0; q < 6; ++q) {
      *reinterpret_cast<float4*>(dst + 4 * q) =
          make_float4(h[4 * q], h[4 * q + 1], h[4 * q + 2], h[4 * q + 3]);
    }
  }
  __syncthreads();

  // ---- P2: vertical 5-max over hmax rows, float4 stores ----
  {
    const int strip = t % 24;        // which float4 of the 96-float out row
    const int g = t / 24;            // row group 0..7 (4 out rows each)
    const int r0 = 4 * g;

    float4 h8[8];
#pragma unroll
    for (int k = 0; k < 8; ++k)
      h8[k] = *reinterpret_cast<const float4*>(&s_h[(r0 + k) * SSTRIDE + strip * 4]);

#pragma unroll
    for (int i = 0; i < 4; ++i) {
      float4 o = max4(max4(max4(h8[i], h8[i + 1]), max4(h8[i + 2], h8[i + 3])),
                      h8[i + 4]);
      float* dst = outimg + (size_t)(h0 + r0 + i) * ROWF + w0f + strip * 4;
      *reinterpret_cast<float4*>(dst) = o;
    }
  }
}

extern "C" void kernel_launch(void* const* d_in, const int* in_sizes, int n_in,
                              void* d_out, int out_size, void* d_ws, size_t ws_size,
                              hipStream_t stream) {
  const float* images = (const float*)d_in[0];
  float* out = (float*)d_out;
  const int nblocks = B * TILES_H * TILES_W;  // 9216
  dilate5_kernel<<<nblocks, 192, 0, stream>>>(images, out);
}